// Round 10
// baseline (426.393 us; speedup 1.0000x reference)
//
#include <hip/hip_runtime.h>
#include <hip/hip_bf16.h>

#define BATCH  64
#define T_ENC  32
#define D_IN   4096
#define T_DEC  20
#define D_WORD 300
#define HID    512
#define FOURH  2048
#define NWG    64
#define ZP     13   // z LDS pad (f32)
// flags layout (u32 idx): [(wg*8+w)*32] per-WAVE step flags (512 x 128B lines);
// [CNT_BASE + i*32] i=0..15 enc bx counters, 16..25 dec bx counters,
// 26..45 dcnt[t] (proj gating, target 512 wave-bumps).
#define CNT_BASE 16384
#define FLAGS_N  17856
#define ZSZ      6656   // floats per zlds buffer (2*4*64*ZP)

typedef __attribute__((ext_vector_type(8))) short short8;
typedef __attribute__((ext_vector_type(4))) float f32x4;
typedef unsigned long long ull;

static __device__ __forceinline__ unsigned short f2bf(float f){
  union { float f; unsigned u; } v; v.f = f;
  unsigned r = v.u + 0x7fffu + ((v.u >> 16) & 1u);   // RNE
  return (unsigned short)(r >> 16);
}
static __device__ __forceinline__ float bf2f(unsigned short b){
  union { unsigned u; float f; } v; v.u = ((unsigned)b) << 16;
  return v.f;
}
static __device__ __forceinline__ float sigm(float x){
  return __builtin_amdgcn_rcpf(1.f + __expf(-x));
}
static __device__ __forceinline__ float tanh_f(float x){
  float e = __expf(2.f * x);
  return 1.f - 2.f * __builtin_amdgcn_rcpf(e + 1.f);
}

// ---------------------------------------------------------------------------
// prep: frames -> bf16, W_enc input rows -> bf16 transposed, zero flags
// (incl. GEMM counters + dcnt), zero Xe (fused accumulates via atomicAdd).
// ---------------------------------------------------------------------------
__global__ __launch_bounds__(256) void prep(
    const float* __restrict__ frames, const float* __restrict__ W_enc,
    unsigned short* __restrict__ fb, unsigned short* __restrict__ wt,
    unsigned* __restrict__ flags, float* __restrict__ Xe)
{
  const int g = blockIdx.x * 256 + threadIdx.x;
  if (blockIdx.x == 0){
    for (int i = threadIdx.x; i < FLAGS_N; i += 256)
      __hip_atomic_store(&flags[i], 0u, __ATOMIC_RELAXED, __HIP_MEMORY_SCOPE_AGENT);
  }
  { // zero Xe: 4194304 floats, 2097152 threads -> float2 each
    float2 z2; z2.x = 0.f; z2.y = 0.f;
    *(float2*)(Xe + (long)g * 2) = z2;
  }
  if (g < 1048576){
    const long base = (long)g * 8;
    float4 x0 = *(const float4*)(frames + base);
    float4 x1 = *(const float4*)(frames + base + 4);
    short8 v;
    v[0] = (short)f2bf(x0.x); v[1] = (short)f2bf(x0.y);
    v[2] = (short)f2bf(x0.z); v[3] = (short)f2bf(x0.w);
    v[4] = (short)f2bf(x1.x); v[5] = (short)f2bf(x1.y);
    v[6] = (short)f2bf(x1.z); v[7] = (short)f2bf(x1.w);
    *(short8*)(fb + base) = v;
  } else {
    const int r  = g - 1048576;
    const int k0 = (r >> 11) << 3;       // 0..4088 step 8
    const int c  = r & 2047;             // coalesced reads across c
    short8 v;
#pragma unroll
    for (int j = 0; j < 8; ++j)
      v[j] = (short)f2bf(W_enc[(long)(k0 + j) * FOURH + c]);
    *(short8*)&wt[(long)c * D_IN + k0] = v;
  }
}

// ---------------------------------------------------------------------------
// Encoder tile, 8-wave (512 thr), 128x128, K-chunk = 1024 (BK=64, 16 iters),
// XOR-swizzled LDS, next-iter reg prefetch (guarded: no dead wrap load).
// Accumulates into Xe via fp32 atomicAdd, bumps per-bx counter (target 64).
// [champion verbatim]
// ---------------------------------------------------------------------------
__device__ __forceinline__ void enc_tile8(
    int bx, int by, int kc,
    const unsigned short* __restrict__ A0, const unsigned short* __restrict__ Wt,
    float* Z, char* smem, unsigned* flags)
{
  char* As = smem;            // [128 rows][128B], byte ^= (row&7)<<4
  char* Bs = smem + 16384;
  const int tid = threadIdx.x;
  const int row0 = bx * 128, col0 = by * 128;

  const int ar = tid >> 2, ah = tid & 3;       // A: 4 thr/row, 16 shorts each
  long asrc;
  {
    int R = row0 + ar;
    int b = R & 63, t = R >> 6;
    asrc = (long)(b * T_ENC + t) * D_IN;
  }
  const int bc = tid & 127, bh = tid >> 7;     // B: 4 thr/col
  const long bsrc = (long)(col0 + bc) * D_IN;
  const long kbase = (long)kc * 1024;

  const int wave = tid >> 6, lane = tid & 63;
  const int wm = (wave >> 2) * 64, wn = (wave & 3) * 32;
  const int lr = lane & 15, lkb = (lane >> 4) << 4, lq = (lane >> 4) << 2;

  f32x4 acc[4][2];
#pragma unroll
  for (int m = 0; m < 4; ++m)
#pragma unroll
    for (int n = 0; n < 2; ++n) acc[m][n] = (f32x4){0.f, 0.f, 0.f, 0.f};

#define ELOAD8(DA, DB, IT) do { \
    const long ka = kbase + (long)(IT) * 64 + ah * 16; \
    const long kb = kbase + (long)(IT) * 64 + bh * 16; \
    _Pragma("unroll") \
    for (int j = 0; j < 2; ++j){ \
      DA[j] = *(const short8*)(A0 + asrc + ka + j * 8); \
      DB[j] = *(const short8*)(Wt + bsrc + kb + j * 8); \
    } \
  } while (0)

  short8 aR[2], bR[2];
  ELOAD8(aR, bR, 0);

  for (int it = 0; it < 16; ++it){
    __syncthreads();   // prev iter's frag reads done
#pragma unroll
    for (int j = 0; j < 2; ++j){
      *(short8*)(As + ar * 128 + ((ah * 32 + j * 16) ^ ((ar & 7) << 4))) = aR[j];
      *(short8*)(Bs + bc * 128 + ((bh * 32 + j * 16) ^ ((bc & 7) << 4))) = bR[j];
    }
    __syncthreads();
    short8 aN[2], bN[2];
    if (it < 15) ELOAD8(aN, bN, it + 1);   // prefetch next K-block (no dead wrap)
#pragma unroll
    for (int kk = 0; kk < 2; ++kk){
      short8 af[4], bfv[2];
#pragma unroll
      for (int m = 0; m < 4; ++m){
        const int r = wm + m * 16 + lr;
        af[m] = *(const short8*)(As + r * 128 + ((kk * 64 + lkb) ^ ((r & 7) << 4)));
      }
#pragma unroll
      for (int n = 0; n < 2; ++n){
        const int r = wn + n * 16 + lr;
        bfv[n] = *(const short8*)(Bs + r * 128 + ((kk * 64 + lkb) ^ ((r & 7) << 4)));
      }
#pragma unroll
      for (int m = 0; m < 4; ++m)
#pragma unroll
        for (int n = 0; n < 2; ++n)
          acc[m][n] = __builtin_amdgcn_mfma_f32_16x16x32_bf16(af[m], bfv[n], acc[m][n], 0, 0, 0);
    }
    if (it < 15){
      aR[0] = aN[0]; aR[1] = aN[1]; bR[0] = bN[0]; bR[1] = bN[1];
    }
  }
#undef ELOAD8

#pragma unroll
  for (int m = 0; m < 4; ++m)
#pragma unroll
    for (int n = 0; n < 2; ++n)
#pragma unroll
      for (int r = 0; r < 4; ++r){
        int gr = row0 + wm + m * 16 + lq + r;
        int gc = col0 + wn + n * 16 + lr;
        __hip_atomic_fetch_add(&Z[(long)gr * FOURH + gc], acc[m][n][r],
                               __ATOMIC_RELAXED, __HIP_MEMORY_SCOPE_AGENT);
      }
  __syncthreads();   // drains vmcnt: all atomics complete before counter bump
  if (tid == 0)
    __hip_atomic_fetch_add(&flags[CNT_BASE + bx * 32], 1u,
                           __ATOMIC_RELAXED, __HIP_MEMORY_SCOPE_AGENT);
}

// ---------------------------------------------------------------------------
// Decoder tile, 8-wave (512 thr), 128x128, K=300. Coherent stores (no bias),
// bumps per-bx counter (target 16).  [champion verbatim]
// ---------------------------------------------------------------------------
__device__ __forceinline__ void dec_tile8(
    int bx, int by, const float* __restrict__ emb, const int* __restrict__ cap,
    const float* __restrict__ W, float* Z, char* smem, unsigned* flags)
{
  constexpr int KLIM  = D_WORD;
  constexpr int ITERS = (KLIM + 31) / 32;
  short* As = (short*)smem;              // [128][40]
  short* Bs = (short*)(smem + 10240);
  const int tid = threadIdx.x;
  const int row0 = bx * 128, col0 = by * 128;

  const int ar = tid >> 2, akq = (tid & 3) * 8;
  long asrc;
  {
    int R = row0 + ar;
    int b = R & 63, t = R >> 6;
    asrc = (long)cap[b * T_DEC + t] * D_WORD;
  }
  const int bc = tid & 127, bkq = (tid >> 7) * 8;

  const int wave = tid >> 6, lane = tid & 63;
  const int wm = (wave >> 2) * 64, wn = (wave & 3) * 32;
  const int lr = lane & 15, lk = (lane >> 4) << 3, lq = (lane >> 4) << 2;

  f32x4 acc[4][2];
#pragma unroll
  for (int m = 0; m < 4; ++m)
#pragma unroll
    for (int n = 0; n < 2; ++n) acc[m][n] = (f32x4){0.f, 0.f, 0.f, 0.f};

  for (int it = 0; it < ITERS; ++it){
    const int k0 = it * 32;
    float av[8], bv[8];
#pragma unroll
    for (int i = 0; i < 8; ++i){
      int k = k0 + akq + i;
      av[i] = (k < KLIM) ? emb[asrc + k] : 0.f;
    }
#pragma unroll
    for (int i = 0; i < 8; ++i){
      int k = k0 + bkq + i;
      bv[i] = (k < KLIM) ? W[(long)k * FOURH + col0 + bc] : 0.f;
    }
    __syncthreads();
    short8 a8, b8;
#pragma unroll
    for (int i = 0; i < 8; ++i){
      a8[i] = (short)f2bf(av[i]);  b8[i] = (short)f2bf(bv[i]);
    }
    *(short8*)&As[ar * 40 + akq] = a8;
    *(short8*)&Bs[bc * 40 + bkq] = b8;
    __syncthreads();
    short8 af[4], bfv[2];
#pragma unroll
    for (int m = 0; m < 4; ++m) af[m]  = *(const short8*)&As[(wm + m * 16 + lr) * 40 + lk];
#pragma unroll
    for (int n = 0; n < 2; ++n) bfv[n] = *(const short8*)&Bs[(wn + n * 16 + lr) * 40 + lk];
#pragma unroll
    for (int m = 0; m < 4; ++m)
#pragma unroll
      for (int n = 0; n < 2; ++n)
        acc[m][n] = __builtin_amdgcn_mfma_f32_16x16x32_bf16(af[m], bfv[n], acc[m][n], 0, 0, 0);
  }

#pragma unroll
  for (int m = 0; m < 4; ++m)
#pragma unroll
    for (int n = 0; n < 2; ++n)
#pragma unroll
      for (int r = 0; r < 4; ++r){
        int gr = row0 + wm + m * 16 + lq + r;
        int gc = col0 + wn + n * 16 + lr;
        __hip_atomic_store(&Z[(long)gr * FOURH + gc], acc[m][n][r],
                           __ATOMIC_RELAXED, __HIP_MEMORY_SCOPE_AGENT);
      }
  __syncthreads();
  if (tid == 0)
    __hip_atomic_fetch_add(&flags[CNT_BASE + (16 + bx) * 32], 1u,
                           __ATOMIC_RELAXED, __HIP_MEMORY_SCOPE_AGENT);
}

// ---------------------------------------------------------------------------
// Projection tail block: waits on dcnt[t] == 512 (per-WAVE bumps), then
// out[b][t][d] = hs[t][b][:] @ W_proj[:, d] + b_proj[d] for its 16 rows.
// ---------------------------------------------------------------------------
__device__ __forceinline__ void proj_tail(
    int p, const unsigned short* __restrict__ hsd, const float* __restrict__ Wp,
    const float* __restrict__ bp, float* __restrict__ out,
    unsigned* flags, char* smem)
{
  float* hl = (float*)smem;              // 16*512 f32 = 32 KB
  const int tid = threadIdx.x;
  const int r0 = p * 16;
  const int t  = r0 >> 6;                // 16 | 64 -> all 16 rows same t

  { // wait: all 512 LSTM waves have stored hs for timestep t
    unsigned* dc = &flags[CNT_BASE + (26 + t) * 32];
    while (__hip_atomic_load(dc, __ATOMIC_RELAXED, __HIP_MEMORY_SCOPE_AGENT) < 512u)
      __builtin_amdgcn_s_sleep(16);
  }
  __builtin_amdgcn_sched_barrier(0);

  for (int idx = tid; idx < 16 * 512; idx += 512)
    hl[idx] = bf2f(hsd[(long)r0 * 512 + idx]);
  __syncthreads();
  if (tid < D_WORD){
    const int d = tid;
    float acc[16];
#pragma unroll
    for (int r = 0; r < 16; ++r) acc[r] = bp[d];
    for (int k = 0; k < 512; ++k){
      float w = Wp[k * D_WORD + d];
#pragma unroll
      for (int r = 0; r < 16; ++r) acc[r] += hl[r * 512 + k] * w;
    }
#pragma unroll
    for (int r = 0; r < 16; ++r){
      int R = r0 + r;
      int tt = R >> 6, b = R & 63;
      out[(long)(b * T_DEC + tt) * D_WORD + d] = acc[r];
    }
  }
}

// ---------------------------------------------------------------------------
// Persistent LSTM recurrence (R10): champion exchange + PER-WAVE flags with
// exact-dependency polling.  Data layout is champion's wg-major slice
// (u16 idx wgid*512 + tid), so fragment row (mh*16+lr) of owner wg o is
// written entirely by owner wave 2mh+(lr>>3) -> each consumer wave needs
// owners [kh*32,+32) x waves {2mh,2mh+1} = 64 flags = 1/lane.  Write-safety
// (h_{q-1} overwrite) needs reader wave vr=(wgid>>5)*4+(wave>>1) of all 64
// wgs = 1 more flag/lane.  Producer wave publishes its one 128B line,
// drains OWN vmcnt, stores OWN flag -- no block barrier on the publish path.
// zlds double-buffered by q&1 (53KB) replaces the old barrier-2 hazard guard.
// ---------------------------------------------------------------------------
#define REC_GEMM(WREG) do { \
  _Pragma("unroll") \
  for (int kk = 0; kk < 8; ++kk){ \
    short8 af; \
    ((ull*)&af)[0] = ha[2 * kk]; \
    ((ull*)&af)[1] = ha[2 * kk + 1]; \
    _Pragma("unroll") \
    for (int n = 0; n < 2; ++n) \
      acc[n] = __builtin_amdgcn_mfma_f32_16x16x32_bf16(af, WREG[kk][n], acc[n], 0, 0, 0); \
  } \
} while (0)

// ---------------------------------------------------------------------------
// Fused kernel: bids 0..63 = persistent LSTM; 64..1247 = input-GEMM tiles
// (enc bx0..7, then dec, then enc bx8..15); 1248..1327 = projection tails.
// ---------------------------------------------------------------------------
__global__ __launch_bounds__(512, 1) void fused(
    const unsigned short* __restrict__ fbf, const unsigned short* __restrict__ wbf,
    float* Xe,
    const float* __restrict__ emb, const int* __restrict__ cap,
    const float* __restrict__ W_dec, float* Xd,
    const float* __restrict__ Wre, const float* __restrict__ Wrd,
    const float* __restrict__ b_enc, const float* __restrict__ b_dec,
    const float* __restrict__ Wp, const float* __restrict__ bp,
    float* __restrict__ out,
    unsigned* hbuf_u, unsigned* hsd_u, unsigned* flags)
{
  __shared__ __align__(16) char smem[65536];
  const int bid = blockIdx.x;

  if (bid >= 64){
    int g = bid - 64;
    if (g < 512)        enc_tile8(g >> 6, g & 15, (g >> 4) & 3, fbf, wbf, Xe, smem, flags);
    else if (g < 672){  int d = g - 512; dec_tile8(d >> 4, d & 15, emb, cap, W_dec, Xd, smem, flags); }
    else if (g < 1184){ int e = g - 672; enc_tile8(8 + (e >> 6), e & 15, (e >> 4) & 3, fbf, wbf, Xe, smem, flags); }
    else                proj_tail(g - 1184, (const unsigned short*)hsd_u, Wp, bp, out, flags, smem);
    return;
  }

  // ---------------- persistent LSTM block ----------------
  const int tid = threadIdx.x, wgid = bid;
  const int wave = tid >> 6, lane = tid & 63;
  const int kh = wave >> 2, mh = wave & 3;
  const int lr = lane & 15, lk = (lane >> 4) << 3;
  const int hi = lane >> 4, lq = (lane >> 4) << 2;

  int ocol[2];
#pragma unroll
  for (int n = 0; n < 2; ++n)
    ocol[n] = (n * 2 + (lr >> 3)) * 512 + wgid * 8 + (lr & 7);

  short8 we[8][2], wd[8][2];
#pragma unroll
  for (int kk = 0; kk < 8; ++kk)
#pragma unroll
    for (int n = 0; n < 2; ++n){
      short8 e, d;
#pragma unroll
      for (int j = 0; j < 8; ++j){
        int k = kh * 256 + kk * 32 + lk + j;
        e[j] = (short)f2bf(Wre[(long)k * FOURH + ocol[n]]);
        d[j] = (short)f2bf(Wrd[(long)k * FOURH + ocol[n]]);
      }
      we[kk][n] = e; wd[kk][n] = d;
    }

  const int cb_ = tid >> 3, cu = tid & 7;
  float c_reg = 0.f;

  float be4[4], bd4[4];
#pragma unroll
  for (int gg = 0; gg < 4; ++gg){
    be4[gg] = b_enc[gg * 512 + wgid * 8 + cu];
    bd4[gg] = b_dec[gg * 512 + wgid * 8 + cu];
  }

  // zero own slice of buffer 0 (wg-major: ull idx wgid*128 + 0..127)
  if (tid < 128)
    __hip_atomic_store((ull*)hbuf_u + wgid * 128 + tid, 0ull,
                       __ATOMIC_RELAXED, __HIP_MEMORY_SCOPE_AGENT);
  __syncthreads();   // implicit vmcnt drain before flag init
  if (tid < 8)
    __hip_atomic_store(&flags[(wgid * 8 + tid) * 32], 1u,
                       __ATOMIC_RELAXED, __HIP_MEMORY_SCOPE_AGENT);

  // per-thread ull offsets of the 8 h-fragments (champion layout)
  int off8[8];
#pragma unroll
  for (int kk = 0; kk < 8; ++kk)
    off8[kk] = (kh * 32 + kk * 4 + hi) * 128 + (mh * 16 + lr) * 2;

  // per-lane poll targets: read-need (owner, producer-wave) + write-safety
  const int fr = ((kh * 32 + (lane >> 1)) * 8 + 2 * mh + (lane & 1)) * 32;
  const int fw = (lane * 8 + ((wgid >> 5) * 4 + (wave >> 1))) * 32;

  for (int q = 0; q < T_ENC + T_DEC; ++q){
    const bool dec = (q >= T_ENC);
    const int tt = dec ? q - T_ENC : q;
    float* Xp = dec ? Xd : Xe;
    float* zlds = (float*)smem + (q & 1) * ZSZ;   // double-buffered partials

    // wait for the input-GEMM columns feeding this timestep (counter is
    // monotonic and covers 2 timesteps -> only poll on even tt)
    if (!(tt & 1)){
      unsigned* xc = dec ? &flags[CNT_BASE + (16 + (tt >> 1)) * 32]
                         : &flags[CNT_BASE + (tt >> 1) * 32];
      const unsigned xtgt = dec ? 16u : 64u;
      while (__hip_atomic_load(xc, __ATOMIC_RELAXED, __HIP_MEMORY_SCOPE_AGENT) < xtgt)
        __builtin_amdgcn_s_sleep(2);
    }
    __builtin_amdgcn_sched_barrier(0);

    const long xb = (long)(tt * BATCH + cb_) * FOURH + wgid * 8 + cu;
    float xi = __hip_atomic_load(&Xp[xb],        __ATOMIC_RELAXED, __HIP_MEMORY_SCOPE_AGENT);
    float xj = __hip_atomic_load(&Xp[xb +  512], __ATOMIC_RELAXED, __HIP_MEMORY_SCOPE_AGENT);
    float xf = __hip_atomic_load(&Xp[xb + 1024], __ATOMIC_RELAXED, __HIP_MEMORY_SCOPE_AGENT);
    float xo = __hip_atomic_load(&Xp[xb + 1536], __ATOMIC_RELAXED, __HIP_MEMORY_SCOPE_AGENT);

    // per-wave exact-dependency poll: 2 flag words/lane
    {
      const unsigned tgt = (unsigned)(q + 1);
      for (;;){
        unsigned f0 = __hip_atomic_load(&flags[fr],
                                        __ATOMIC_RELAXED, __HIP_MEMORY_SCOPE_AGENT);
        unsigned f1 = __hip_atomic_load(&flags[fw],
                                        __ATOMIC_RELAXED, __HIP_MEMORY_SCOPE_AGENT);
        if (__all((int)(f0 >= tgt && f1 >= tgt))) break;
        __builtin_amdgcn_s_sleep(1);
      }
    }
    __builtin_amdgcn_sched_barrier(0);

    // direct h fragment loads (champion): fragment (kk,hi) lives in owner wg
    const ull* rb = (const ull*)hbuf_u + (q & 1) * 8192;
    ull ha[16];
#pragma unroll
    for (int kk = 0; kk < 8; ++kk){
      const int o = off8[kk];
      ha[2 * kk]     = __hip_atomic_load(rb + o,     __ATOMIC_RELAXED, __HIP_MEMORY_SCOPE_AGENT);
      ha[2 * kk + 1] = __hip_atomic_load(rb + o + 1, __ATOMIC_RELAXED, __HIP_MEMORY_SCOPE_AGENT);
    }

    f32x4 acc[2];
#pragma unroll
    for (int n = 0; n < 2; ++n) acc[n] = (f32x4){0.f, 0.f, 0.f, 0.f};
    __builtin_amdgcn_s_setprio(1);
    if (!dec) REC_GEMM(we); else REC_GEMM(wd);
    __builtin_amdgcn_s_setprio(0);

#pragma unroll
    for (int n = 0; n < 2; ++n){
      const int g = n * 2 + (lr >> 3), u = lr & 7;
#pragma unroll
      for (int r = 0; r < 4; ++r){
        const int row = mh * 16 + lq + r;
        zlds[((kh * 4 + g) * 64 + row) * ZP + u] = acc[n][r];
      }
    }
    __syncthreads();   // barrier 1: zlds writes visible to readers

    const int zb = cb_ * ZP + cu;
    float zi = zlds[(0 * 64) * ZP + zb] + zlds[(4 * 64) * ZP + zb] + xi + (dec ? bd4[0] : be4[0]);
    float zj = zlds[(1 * 64) * ZP + zb] + zlds[(5 * 64) * ZP + zb] + xj + (dec ? bd4[1] : be4[1]);
    float zf = zlds[(2 * 64) * ZP + zb] + zlds[(6 * 64) * ZP + zb] + xf + (dec ? bd4[2] : be4[2]);
    float zo = zlds[(3 * 64) * ZP + zb] + zlds[(7 * 64) * ZP + zb] + xo + (dec ? bd4[3] : be4[3]);
    c_reg = c_reg * sigm(zf + 1.f) + sigm(zi) * tanh_f(zj);
    float hn = tanh_f(c_reg) * sigm(zo);
    unsigned short hb = f2bf(hn);

    // wg-major h store (champion layout): wave's 64 lanes = one 128B line
    __hip_atomic_store(&((unsigned short*)hbuf_u)[((q + 1) & 1) * 32768 + wgid * 512 + tid],
                       hb, __ATOMIC_RELAXED, __HIP_MEMORY_SCOPE_AGENT);
    if (dec)
      __hip_atomic_store(&((unsigned short*)hsd_u)[(tt * BATCH + cb_) * 512 + wgid * 8 + cu],
                         hb, __ATOMIC_RELAXED, __HIP_MEMORY_SCOPE_AGENT);

    // per-wave drain + per-wave flag (NO block barrier on the publish path)
    asm volatile("s_waitcnt vmcnt(0)" ::: "memory");
    __builtin_amdgcn_sched_barrier(0);
    if (lane == 0)
      __hip_atomic_store(&flags[(wgid * 8 + wave) * 32], (unsigned)(q + 2),
                         __ATOMIC_RELAXED, __HIP_MEMORY_SCOPE_AGENT);
    if (dec && lane == 1)
      __hip_atomic_fetch_add(&flags[CNT_BASE + (26 + tt) * 32], 1u,
                             __ATOMIC_RELAXED, __HIP_MEMORY_SCOPE_AGENT);
  }
}

// ---------------------------------------------------------------------------
extern "C" void kernel_launch(void* const* d_in, const int* in_sizes, int n_in,
                              void* d_out, int out_size, void* d_ws, size_t ws_size,
                              hipStream_t stream)
{
  const float* frames  = (const float*)d_in[0];
  const float* emb     = (const float*)d_in[1];
  const float* W_enc   = (const float*)d_in[2];
  const float* b_enc   = (const float*)d_in[3];
  const float* W_dec   = (const float*)d_in[4];
  const float* b_dec   = (const float*)d_in[5];
  const float* W_proj  = (const float*)d_in[6];
  const float* b_proj  = (const float*)d_in[7];
  const int*   caption = (const int*)d_in[8];

  char* ws = (char*)d_ws;
  float*          Xe    = (float*)(ws + 0);                 // 16 MB
  float*          Xd    = (float*)(ws + 16777216);          // 10 MB
  unsigned*       hbuf  = (unsigned*)(ws + 27262976);       // 128 KB (u16 x 2 buf)
  unsigned*       hsd   = (unsigned*)(ws + 27394048);       // 1.25 MB (u16)
  unsigned*       flags = (unsigned*)(ws + 28704768);       // 72 KB (wave flags + counters)
  unsigned short* fbf   = (unsigned short*)(ws + 28778496); // 16.78 MB (frames bf16)
  unsigned short* wbf   = (unsigned short*)(ws + 45555712); // 16.78 MB (W_enc^T bf16)
  float* out = (float*)d_out;

  prep<<<8192, 256, 0, stream>>>(frames, W_enc, fbf, wbf, flags, Xe);
  fused<<<64 + 1184 + 80, 512, 0, stream>>>(
      fbf, wbf, Xe, emb, caption, W_dec, Xd,
      W_enc + (long)D_IN * FOURH,
      W_dec + (long)D_WORD * FOURH,
      b_enc, b_dec, W_proj, b_proj, out,
      hbuf, hsd, flags);
}

// Round 11
// 294.404 us; speedup vs baseline: 1.4483x; 1.4483x over previous
//
#include <hip/hip_runtime.h>
#include <hip/hip_bf16.h>

#define BATCH  64
#define T_ENC  32
#define D_IN   4096
#define T_DEC  20
#define D_WORD 300
#define HID    512
#define FOURH  2048
#define NWG    64
#define FPAD   32   // flags stride in u32 (128B)  [R4-proven]
#define ZP     13   // z LDS pad (f32)
// flags layout (u32 idx): [wgid*FPAD] step flags (exclusive lines);
// [2048 + i*32] i=0..15 enc bx counters, i=16..25 dec bx counters,
// i=26..45 dcnt[t] (proj gating). Total 3520 u32.
#define CNT_BASE 2048
#define FLAGS_N  3520

typedef __attribute__((ext_vector_type(8))) short short8;
typedef __attribute__((ext_vector_type(4))) float f32x4;
typedef unsigned long long ull;

static __device__ __forceinline__ unsigned short f2bf(float f){
  union { float f; unsigned u; } v; v.f = f;
  unsigned r = v.u + 0x7fffu + ((v.u >> 16) & 1u);   // RNE
  return (unsigned short)(r >> 16);
}
static __device__ __forceinline__ float bf2f(unsigned short b){
  union { unsigned u; float f; } v; v.u = ((unsigned)b) << 16;
  return v.f;
}
static __device__ __forceinline__ float sigm(float x){
  return __builtin_amdgcn_rcpf(1.f + __expf(-x));
}
static __device__ __forceinline__ float tanh_f(float x){
  float e = __expf(2.f * x);
  return 1.f - 2.f * __builtin_amdgcn_rcpf(e + 1.f);
}

// ---------------------------------------------------------------------------
// prep: frames -> bf16, W_enc input rows -> bf16 transposed, zero flags
// (incl. GEMM counters + dcnt), zero Xe (fused accumulates via atomicAdd).
// ---------------------------------------------------------------------------
__global__ __launch_bounds__(256) void prep(
    const float* __restrict__ frames, const float* __restrict__ W_enc,
    unsigned short* __restrict__ fb, unsigned short* __restrict__ wt,
    unsigned* __restrict__ flags, float* __restrict__ Xe)
{
  const int g = blockIdx.x * 256 + threadIdx.x;
  if (blockIdx.x == 0){
    for (int i = threadIdx.x; i < FLAGS_N; i += 256)
      __hip_atomic_store(&flags[i], 0u, __ATOMIC_RELAXED, __HIP_MEMORY_SCOPE_AGENT);
  }
  { // zero Xe: 4194304 floats, 2097152 threads -> float2 each
    float2 z2; z2.x = 0.f; z2.y = 0.f;
    *(float2*)(Xe + (long)g * 2) = z2;
  }
  if (g < 1048576){
    const long base = (long)g * 8;
    float4 x0 = *(const float4*)(frames + base);
    float4 x1 = *(const float4*)(frames + base + 4);
    short8 v;
    v[0] = (short)f2bf(x0.x); v[1] = (short)f2bf(x0.y);
    v[2] = (short)f2bf(x0.z); v[3] = (short)f2bf(x0.w);
    v[4] = (short)f2bf(x1.x); v[5] = (short)f2bf(x1.y);
    v[6] = (short)f2bf(x1.z); v[7] = (short)f2bf(x1.w);
    *(short8*)(fb + base) = v;
  } else {
    const int r  = g - 1048576;
    const int k0 = (r >> 11) << 3;       // 0..4088 step 8
    const int c  = r & 2047;             // coalesced reads across c
    short8 v;
#pragma unroll
    for (int j = 0; j < 8; ++j)
      v[j] = (short)f2bf(W_enc[(long)(k0 + j) * FOURH + c]);
    *(short8*)&wt[(long)c * D_IN + k0] = v;
  }
}

// ---------------------------------------------------------------------------
// Encoder tile, 8-wave (512 thr), 128x128, K-chunk = 1024 (BK=64, 16 iters),
// XOR-swizzled LDS, next-iter reg prefetch (guarded: no dead wrap load).
// Accumulates into Xe via fp32 atomicAdd, bumps per-bx counter (target 64).
// ---------------------------------------------------------------------------
__device__ __forceinline__ void enc_tile8(
    int bx, int by, int kc,
    const unsigned short* __restrict__ A0, const unsigned short* __restrict__ Wt,
    float* Z, char* smem, unsigned* flags)
{
  char* As = smem;            // [128 rows][128B], byte ^= (row&7)<<4
  char* Bs = smem + 16384;
  const int tid = threadIdx.x;
  const int row0 = bx * 128, col0 = by * 128;

  const int ar = tid >> 2, ah = tid & 3;       // A: 4 thr/row, 16 shorts each
  long asrc;
  {
    int R = row0 + ar;
    int b = R & 63, t = R >> 6;
    asrc = (long)(b * T_ENC + t) * D_IN;
  }
  const int bc = tid & 127, bh = tid >> 7;     // B: 4 thr/col
  const long bsrc = (long)(col0 + bc) * D_IN;
  const long kbase = (long)kc * 1024;

  const int wave = tid >> 6, lane = tid & 63;
  const int wm = (wave >> 2) * 64, wn = (wave & 3) * 32;
  const int lr = lane & 15, lkb = (lane >> 4) << 4, lq = (lane >> 4) << 2;

  f32x4 acc[4][2];
#pragma unroll
  for (int m = 0; m < 4; ++m)
#pragma unroll
    for (int n = 0; n < 2; ++n) acc[m][n] = (f32x4){0.f, 0.f, 0.f, 0.f};

#define ELOAD8(DA, DB, IT) do { \
    const long ka = kbase + (long)(IT) * 64 + ah * 16; \
    const long kb = kbase + (long)(IT) * 64 + bh * 16; \
    _Pragma("unroll") \
    for (int j = 0; j < 2; ++j){ \
      DA[j] = *(const short8*)(A0 + asrc + ka + j * 8); \
      DB[j] = *(const short8*)(Wt + bsrc + kb + j * 8); \
    } \
  } while (0)

  short8 aR[2], bR[2];
  ELOAD8(aR, bR, 0);

  for (int it = 0; it < 16; ++it){
    __syncthreads();   // prev iter's frag reads done
#pragma unroll
    for (int j = 0; j < 2; ++j){
      *(short8*)(As + ar * 128 + ((ah * 32 + j * 16) ^ ((ar & 7) << 4))) = aR[j];
      *(short8*)(Bs + bc * 128 + ((bh * 32 + j * 16) ^ ((bc & 7) << 4))) = bR[j];
    }
    __syncthreads();
    short8 aN[2], bN[2];
    if (it < 15) ELOAD8(aN, bN, it + 1);   // prefetch next K-block (no dead wrap)
#pragma unroll
    for (int kk = 0; kk < 2; ++kk){
      short8 af[4], bfv[2];
#pragma unroll
      for (int m = 0; m < 4; ++m){
        const int r = wm + m * 16 + lr;
        af[m] = *(const short8*)(As + r * 128 + ((kk * 64 + lkb) ^ ((r & 7) << 4)));
      }
#pragma unroll
      for (int n = 0; n < 2; ++n){
        const int r = wn + n * 16 + lr;
        bfv[n] = *(const short8*)(Bs + r * 128 + ((kk * 64 + lkb) ^ ((r & 7) << 4)));
      }
#pragma unroll
      for (int m = 0; m < 4; ++m)
#pragma unroll
        for (int n = 0; n < 2; ++n)
          acc[m][n] = __builtin_amdgcn_mfma_f32_16x16x32_bf16(af[m], bfv[n], acc[m][n], 0, 0, 0);
    }
    if (it < 15){
      aR[0] = aN[0]; aR[1] = aN[1]; bR[0] = bN[0]; bR[1] = bN[1];
    }
  }
#undef ELOAD8

#pragma unroll
  for (int m = 0; m < 4; ++m)
#pragma unroll
    for (int n = 0; n < 2; ++n)
#pragma unroll
      for (int r = 0; r < 4; ++r){
        int gr = row0 + wm + m * 16 + lq + r;
        int gc = col0 + wn + n * 16 + lr;
        __hip_atomic_fetch_add(&Z[(long)gr * FOURH + gc], acc[m][n][r],
                               __ATOMIC_RELAXED, __HIP_MEMORY_SCOPE_AGENT);
      }
  __syncthreads();   // drains vmcnt: all atomics complete before counter bump
  if (tid == 0)
    __hip_atomic_fetch_add(&flags[CNT_BASE + bx * 32], 1u,
                           __ATOMIC_RELAXED, __HIP_MEMORY_SCOPE_AGENT);
}

// ---------------------------------------------------------------------------
// Decoder tile, 8-wave (512 thr), 128x128, K=300. Coherent stores (no bias),
// bumps per-bx counter (target 16).
// ---------------------------------------------------------------------------
__device__ __forceinline__ void dec_tile8(
    int bx, int by, const float* __restrict__ emb, const int* __restrict__ cap,
    const float* __restrict__ W, float* Z, char* smem, unsigned* flags)
{
  constexpr int KLIM  = D_WORD;
  constexpr int ITERS = (KLIM + 31) / 32;
  short* As = (short*)smem;              // [128][40]
  short* Bs = (short*)(smem + 10240);
  const int tid = threadIdx.x;
  const int row0 = bx * 128, col0 = by * 128;

  const int ar = tid >> 2, akq = (tid & 3) * 8;
  long asrc;
  {
    int R = row0 + ar;
    int b = R & 63, t = R >> 6;
    asrc = (long)cap[b * T_DEC + t] * D_WORD;
  }
  const int bc = tid & 127, bkq = (tid >> 7) * 8;

  const int wave = tid >> 6, lane = tid & 63;
  const int wm = (wave >> 2) * 64, wn = (wave & 3) * 32;
  const int lr = lane & 15, lk = (lane >> 4) << 3, lq = (lane >> 4) << 2;

  f32x4 acc[4][2];
#pragma unroll
  for (int m = 0; m < 4; ++m)
#pragma unroll
    for (int n = 0; n < 2; ++n) acc[m][n] = (f32x4){0.f, 0.f, 0.f, 0.f};

  for (int it = 0; it < ITERS; ++it){
    const int k0 = it * 32;
    float av[8], bv[8];
#pragma unroll
    for (int i = 0; i < 8; ++i){
      int k = k0 + akq + i;
      av[i] = (k < KLIM) ? emb[asrc + k] : 0.f;
    }
#pragma unroll
    for (int i = 0; i < 8; ++i){
      int k = k0 + bkq + i;
      bv[i] = (k < KLIM) ? W[(long)k * FOURH + col0 + bc] : 0.f;
    }
    __syncthreads();
    short8 a8, b8;
#pragma unroll
    for (int i = 0; i < 8; ++i){
      a8[i] = (short)f2bf(av[i]);  b8[i] = (short)f2bf(bv[i]);
    }
    *(short8*)&As[ar * 40 + akq] = a8;
    *(short8*)&Bs[bc * 40 + bkq] = b8;
    __syncthreads();
    short8 af[4], bfv[2];
#pragma unroll
    for (int m = 0; m < 4; ++m) af[m]  = *(const short8*)&As[(wm + m * 16 + lr) * 40 + lk];
#pragma unroll
    for (int n = 0; n < 2; ++n) bfv[n] = *(const short8*)&Bs[(wn + n * 16 + lr) * 40 + lk];
#pragma unroll
    for (int m = 0; m < 4; ++m)
#pragma unroll
      for (int n = 0; n < 2; ++n)
        acc[m][n] = __builtin_amdgcn_mfma_f32_16x16x32_bf16(af[m], bfv[n], acc[m][n], 0, 0, 0);
  }

#pragma unroll
  for (int m = 0; m < 4; ++m)
#pragma unroll
    for (int n = 0; n < 2; ++n)
#pragma unroll
      for (int r = 0; r < 4; ++r){
        int gr = row0 + wm + m * 16 + lq + r;
        int gc = col0 + wn + n * 16 + lr;
        __hip_atomic_store(&Z[(long)gr * FOURH + gc], acc[m][n][r],
                           __ATOMIC_RELAXED, __HIP_MEMORY_SCOPE_AGENT);
      }
  __syncthreads();
  if (tid == 0)
    __hip_atomic_fetch_add(&flags[CNT_BASE + (16 + bx) * 32], 1u,
                           __ATOMIC_RELAXED, __HIP_MEMORY_SCOPE_AGENT);
}

// ---------------------------------------------------------------------------
// Projection tail block: waits on dcnt[t] == 64 (single non-critical line),
// then out[b][t][d] = hs[t][b][:] @ W_proj[:, d] + b_proj[d] for its 16 rows.
// ---------------------------------------------------------------------------
__device__ __forceinline__ void proj_tail(
    int p, const unsigned short* __restrict__ hsd, const float* __restrict__ Wp,
    const float* __restrict__ bp, float* __restrict__ out,
    unsigned* flags, char* smem)
{
  float* hl = (float*)smem;              // 16*512 f32 = 32 KB
  const int tid = threadIdx.x;
  const int r0 = p * 16;
  const int t  = r0 >> 6;                // 16 | 64 -> all 16 rows same t

  { // wait: all 64 LSTM wgs have stored hs for timestep t
    unsigned* dc = &flags[CNT_BASE + (26 + t) * 32];
    while (__hip_atomic_load(dc, __ATOMIC_RELAXED, __HIP_MEMORY_SCOPE_AGENT) < 64u)
      __builtin_amdgcn_s_sleep(16);
  }
  __builtin_amdgcn_sched_barrier(0);

  for (int idx = tid; idx < 16 * 512; idx += 512)
    hl[idx] = bf2f(hsd[(long)r0 * 512 + idx]);
  __syncthreads();
  if (tid < D_WORD){
    const int d = tid;
    float acc[16];
#pragma unroll
    for (int r = 0; r < 16; ++r) acc[r] = bp[d];
    for (int k = 0; k < 512; ++k){
      float w = Wp[k * D_WORD + d];
#pragma unroll
      for (int r = 0; r < 16; ++r) acc[r] += hl[r * 512 + k] * w;
    }
#pragma unroll
    for (int r = 0; r < 16; ++r){
      int R = r0 + r;
      int tt = R >> 6, b = R & 63;
      out[(long)(b * T_DEC + tt) * D_WORD + d] = acc[r];
    }
  }
}

// ---------------------------------------------------------------------------
// Persistent LSTM recurrence core (champion, 295 us): h-exchange is DIRECT
// global->reg (each fragment read exactly once -> no LDS relay, 2 barriers
// per step). hbuf is wg-major: [buf][wgid][b][8] u16 so each wg's per-step
// 1KB h-slice store is contiguous and line-private (fast vmcnt drain, no
// cross-wg false sharing). setprio(1) scoped to the MFMA cluster.
// 10 structural variants (tagged-data R5, wave-autonomous R6, full-K R7,
// bg-local R8, per-wave flags R10) all regressed vs this protocol.
// ---------------------------------------------------------------------------
#define REC_GEMM(WREG) do { \
  _Pragma("unroll") \
  for (int kk = 0; kk < 8; ++kk){ \
    short8 af; \
    ((ull*)&af)[0] = ha[2 * kk]; \
    ((ull*)&af)[1] = ha[2 * kk + 1]; \
    _Pragma("unroll") \
    for (int n = 0; n < 2; ++n) \
      acc[n] = __builtin_amdgcn_mfma_f32_16x16x32_bf16(af, WREG[kk][n], acc[n], 0, 0, 0); \
  } \
} while (0)

// ---------------------------------------------------------------------------
// Fused kernel: bids 0..63 = persistent LSTM; 64..1247 = input-GEMM tiles
// (enc bx0..7, then dec, then enc bx8..15); 1248..1327 = projection tails.
// ---------------------------------------------------------------------------
__global__ __launch_bounds__(512, 1) void fused(
    const unsigned short* __restrict__ fbf, const unsigned short* __restrict__ wbf,
    float* Xe,
    const float* __restrict__ emb, const int* __restrict__ cap,
    const float* __restrict__ W_dec, float* Xd,
    const float* __restrict__ Wre, const float* __restrict__ Wrd,
    const float* __restrict__ b_enc, const float* __restrict__ b_dec,
    const float* __restrict__ Wp, const float* __restrict__ bp,
    float* __restrict__ out,
    unsigned* hbuf_u, unsigned* hsd_u, unsigned* flags)
{
  __shared__ __align__(16) char smem[65536];
  const int bid = blockIdx.x;

  if (bid >= 64){
    int g = bid - 64;
    if (g < 512)        enc_tile8(g >> 6, g & 15, (g >> 4) & 3, fbf, wbf, Xe, smem, flags);
    else if (g < 672){  int d = g - 512; dec_tile8(d >> 4, d & 15, emb, cap, W_dec, Xd, smem, flags); }
    else if (g < 1184){ int e = g - 672; enc_tile8(8 + (e >> 6), e & 15, (e >> 4) & 3, fbf, wbf, Xe, smem, flags); }
    else                proj_tail(g - 1184, (const unsigned short*)hsd_u, Wp, bp, out, flags, smem);
    return;
  }

  // ---------------- persistent LSTM block ----------------
  float* zlds = (float*)smem;              // 26.6 KB gate partials (only LDS use)
  const int tid = threadIdx.x, wgid = bid;
  const int wave = tid >> 6, lane = tid & 63;
  const int kh = wave >> 2, mh = wave & 3;
  const int lr = lane & 15, lk = (lane >> 4) << 3;
  const int hi = lane >> 4, lq = (lane >> 4) << 2;

  int ocol[2];
#pragma unroll
  for (int n = 0; n < 2; ++n)
    ocol[n] = (n * 2 + (lr >> 3)) * 512 + wgid * 8 + (lr & 7);

  short8 we[8][2], wd[8][2];
#pragma unroll
  for (int kk = 0; kk < 8; ++kk)
#pragma unroll
    for (int n = 0; n < 2; ++n){
      short8 e, d;
#pragma unroll
      for (int j = 0; j < 8; ++j){
        int k = kh * 256 + kk * 32 + lk + j;
        e[j] = (short)f2bf(Wre[(long)k * FOURH + ocol[n]]);
        d[j] = (short)f2bf(Wrd[(long)k * FOURH + ocol[n]]);
      }
      we[kk][n] = e; wd[kk][n] = d;
    }

  const int cb_ = tid >> 3, cu = tid & 7;
  float c_reg = 0.f;

  float be4[4], bd4[4];
#pragma unroll
  for (int gg = 0; gg < 4; ++gg){
    be4[gg] = b_enc[gg * 512 + wgid * 8 + cu];
    bd4[gg] = b_dec[gg * 512 + wgid * 8 + cu];
  }

  // zero own slice of buffer 0 (wg-major: ull idx wgid*128 + 0..127)
  if (tid < 128)
    __hip_atomic_store((ull*)hbuf_u + wgid * 128 + tid, 0ull,
                       __ATOMIC_RELAXED, __HIP_MEMORY_SCOPE_AGENT);
  __syncthreads();
  if (tid == 0)
    __hip_atomic_store(&flags[wgid * FPAD], 1u,
                       __ATOMIC_RELAXED, __HIP_MEMORY_SCOPE_AGENT);

  const bool mine = (lane != wgid);

  // per-thread ull offsets of the 8 h-fragments (4 consecutive ulls each)
  int off8[8];
#pragma unroll
  for (int kk = 0; kk < 8; ++kk)
    off8[kk] = (kh * 32 + kk * 4 + hi) * 128 + (mh * 16 + lr) * 2;

  for (int q = 0; q < T_ENC + T_DEC; ++q){
    const bool dec = (q >= T_ENC);
    const int tt = dec ? q - T_ENC : q;
    float* Xp = dec ? Xd : Xe;

    // wait for the input-GEMM columns feeding this timestep (counter is
    // monotonic and covers 2 timesteps -> only poll on even tt)
    if (!(tt & 1)){
      unsigned* xc = dec ? &flags[CNT_BASE + (16 + (tt >> 1)) * 32]
                         : &flags[CNT_BASE + (tt >> 1) * 32];
      const unsigned xtgt = dec ? 16u : 64u;
      while (__hip_atomic_load(xc, __ATOMIC_RELAXED, __HIP_MEMORY_SCOPE_AGENT) < xtgt)
        __builtin_amdgcn_s_sleep(2);
    }
    __builtin_amdgcn_sched_barrier(0);

    const long xb = (long)(tt * BATCH + cb_) * FOURH + wgid * 8 + cu;
    float xi = __hip_atomic_load(&Xp[xb],        __ATOMIC_RELAXED, __HIP_MEMORY_SCOPE_AGENT);
    float xj = __hip_atomic_load(&Xp[xb +  512], __ATOMIC_RELAXED, __HIP_MEMORY_SCOPE_AGENT);
    float xf = __hip_atomic_load(&Xp[xb + 1024], __ATOMIC_RELAXED, __HIP_MEMORY_SCOPE_AGENT);
    float xo = __hip_atomic_load(&Xp[xb + 1536], __ATOMIC_RELAXED, __HIP_MEMORY_SCOPE_AGENT);

    {
      const unsigned tgt = (unsigned)(q + 1);
      for (;;){
        unsigned f = tgt;
        if (mine) f = __hip_atomic_load(&flags[lane * FPAD],
                                        __ATOMIC_RELAXED, __HIP_MEMORY_SCOPE_AGENT);
        if (__all((int)(f >= tgt))) break;
        __builtin_amdgcn_s_sleep(1);
      }
    }
    __builtin_amdgcn_sched_barrier(0);

    // direct h fragment loads: fragment (kk,hi) lives in owner wg
    // w = kh*32 + kk*4 + hi at ull idx w*128 + (mh*16+lr)*2 (+1)
    const ull* rb = (const ull*)hbuf_u + (q & 1) * 8192;
    ull ha[16];
#pragma unroll
    for (int kk = 0; kk < 8; ++kk){
      const int o = off8[kk];
      ha[2 * kk]     = __hip_atomic_load(rb + o,     __ATOMIC_RELAXED, __HIP_MEMORY_SCOPE_AGENT);
      ha[2 * kk + 1] = __hip_atomic_load(rb + o + 1, __ATOMIC_RELAXED, __HIP_MEMORY_SCOPE_AGENT);
    }

    f32x4 acc[2];
#pragma unroll
    for (int n = 0; n < 2; ++n) acc[n] = (f32x4){0.f, 0.f, 0.f, 0.f};
    __builtin_amdgcn_s_setprio(1);
    if (!dec) REC_GEMM(we); else REC_GEMM(wd);
    __builtin_amdgcn_s_setprio(0);

#pragma unroll
    for (int n = 0; n < 2; ++n){
      const int g = n * 2 + (lr >> 3), u = lr & 7;
#pragma unroll
      for (int r = 0; r < 4; ++r){
        const int row = mh * 16 + lq + r;
        zlds[((kh * 4 + g) * 64 + row) * ZP + u] = acc[n][r];
      }
    }
    __syncthreads();

    const int zb = cb_ * ZP + cu;
    float zi = zlds[(0 * 64) * ZP + zb] + zlds[(4 * 64) * ZP + zb] + xi + (dec ? bd4[0] : be4[0]);
    float zj = zlds[(1 * 64) * ZP + zb] + zlds[(5 * 64) * ZP + zb] + xj + (dec ? bd4[1] : be4[1]);
    float zf = zlds[(2 * 64) * ZP + zb] + zlds[(6 * 64) * ZP + zb] + xf + (dec ? bd4[2] : be4[2]);
    float zo = zlds[(3 * 64) * ZP + zb] + zlds[(7 * 64) * ZP + zb] + xo + (dec ? bd4[3] : be4[3]);
    c_reg = c_reg * sigm(zf + 1.f) + sigm(zi) * tanh_f(zj);
    float hn = tanh_f(c_reg) * sigm(zo);
    unsigned short hb = f2bf(hn);

    // wg-major h store: contiguous 1KB per wg (u16 idx = buf*32768 + wgid*512 + tid)
    __hip_atomic_store(&((unsigned short*)hbuf_u)[((q + 1) & 1) * 32768 + wgid * 512 + tid],
                       hb, __ATOMIC_RELAXED, __HIP_MEMORY_SCOPE_AGENT);
    if (dec)
      __hip_atomic_store(&((unsigned short*)hsd_u)[(tt * BATCH + cb_) * 512 + wgid * 8 + cu],
                         hb, __ATOMIC_RELAXED, __HIP_MEMORY_SCOPE_AGENT);

    __syncthreads();   // drains vmcnt: h/hsd stores visible before flag/dcnt
    if (tid == 0)
      __hip_atomic_store(&flags[wgid * FPAD], (unsigned)(q + 2),
                         __ATOMIC_RELAXED, __HIP_MEMORY_SCOPE_AGENT);
    if (dec && tid == 64)
      __hip_atomic_fetch_add(&flags[CNT_BASE + (26 + tt) * 32], 1u,
                             __ATOMIC_RELAXED, __HIP_MEMORY_SCOPE_AGENT);
  }
}

// ---------------------------------------------------------------------------
extern "C" void kernel_launch(void* const* d_in, const int* in_sizes, int n_in,
                              void* d_out, int out_size, void* d_ws, size_t ws_size,
                              hipStream_t stream)
{
  const float* frames  = (const float*)d_in[0];
  const float* emb     = (const float*)d_in[1];
  const float* W_enc   = (const float*)d_in[2];
  const float* b_enc   = (const float*)d_in[3];
  const float* W_dec   = (const float*)d_in[4];
  const float* b_dec   = (const float*)d_in[5];
  const float* W_proj  = (const float*)d_in[6];
  const float* b_proj  = (const float*)d_in[7];
  const int*   caption = (const int*)d_in[8];

  char* ws = (char*)d_ws;
  float*          Xe    = (float*)(ws + 0);                 // 16 MB
  float*          Xd    = (float*)(ws + 16777216);          // 10 MB
  unsigned*       hbuf  = (unsigned*)(ws + 27262976);       // 128 KB (u16 x 2 buf)
  unsigned*       hsd   = (unsigned*)(ws + 27394048);       // 1.25 MB (u16)
  unsigned*       flags = (unsigned*)(ws + 28704768);       // 16 KB (flags+counters+dcnt)
  unsigned short* fbf   = (unsigned short*)(ws + 28721152); // 16.78 MB (frames bf16)
  unsigned short* wbf   = (unsigned short*)(ws + 45498368); // 16.78 MB (W_enc^T bf16)
  float* out = (float*)d_out;

  prep<<<8192, 256, 0, stream>>>(frames, W_enc, fbf, wbf, flags, Xe);
  fused<<<64 + 1184 + 80, 512, 0, stream>>>(
      fbf, wbf, Xe, emb, caption, W_dec, Xd,
      W_enc + (long)D_IN * FOURH,
      W_dec + (long)D_WORD * FOURH,
      b_enc, b_dec, W_proj, b_proj, out,
      hbuf, hsd, flags);
}